// Round 7
// baseline (433.228 us; speedup 1.0000x reference)
//
#include <hip/hip_runtime.h>
#include <math.h>

#define NN 20000
#define EE 320000
#define DD 256
#define ETOT (EE + NN)

typedef __attribute__((ext_vector_type(8))) short bf8;
typedef __attribute__((ext_vector_type(4))) float f32x4;

__device__ __forceinline__ float gelu_exact(float x) {
    return 0.5f * x * (1.0f + erff(x * 0.70710678118654752f));
}

// round-to-nearest-even f32 -> bf16 bits
__device__ __forceinline__ unsigned short f2bf(float v) {
    unsigned u = __float_as_uint(v);
    u += 0x7fffu + ((u >> 16) & 1u);
    return (unsigned short)(u >> 16);
}
__device__ __forceinline__ float bf2f(unsigned short h) {
    return __uint_as_float(((unsigned)h) << 16);
}
__device__ __forceinline__ void split2(float v, unsigned short& hi, unsigned short& lo) {
    hi = f2bf(v);
    lo = f2bf(v - bf2f(hi));
}

// ---------------- row-normalize + split X; zero s/d buffers; init deg ----------------
__global__ __launch_bounds__(256) void norm_k(const float* __restrict__ X,
                                              unsigned short* __restrict__ Xh,
                                              unsigned short* __restrict__ Xl,
                                              float* __restrict__ sdZero,  // 6*NN floats
                                              int* __restrict__ deg) {
    int t = threadIdx.x;
    int bid = blockIdx.x;  // 0..4999
    if (t < 24) sdZero[bid * 24 + t] = 0.0f;
    if (t >= 32 && t < 36) deg[bid * 4 + (t - 32)] = 1;

    int wave = (bid * 256 + t) >> 6;
    int lane = t & 63;
    const float4 v = *(const float4*)&X[wave * DD + lane * 4];
    float ss = v.x * v.x + v.y * v.y + v.z * v.z + v.w * v.w;
    for (int off = 32; off > 0; off >>= 1) ss += __shfl_down(ss, off, 64);
    ss = __shfl(ss, 0, 64);
    float n = sqrtf(ss);
    if (n == 0.0f) n = 1e-8f;
    float inv = 1.0f / n;
    float o[4] = {v.x * inv, v.y * inv, v.z * inv, v.w * inv};
    ushort4 hv, lv;
    split2(o[0], hv.x, lv.x);
    split2(o[1], hv.y, lv.y);
    split2(o[2], hv.z, lv.z);
    split2(o[3], hv.w, lv.w);
    *(ushort4*)&Xh[wave * DD + lane * 4] = hv;
    *(ushort4*)&Xl[wave * DD + lane * 4] = lv;
}

// ---------------- W transpose + hi/lo split for all 3 layers (z = layer) ----------------
__global__ __launch_bounds__(256) void splitw_k(const float* __restrict__ W1, const float* __restrict__ W2,
                                                const float* __restrict__ W3, unsigned short* __restrict__ Whl) {
    __shared__ float tile[64][65];
    int t = threadIdx.x;
    int k0 = blockIdx.x * 64;
    int c0 = blockIdx.y * 64;
    int z = blockIdx.z;
    const float* W = (z == 0) ? W1 : (z == 1) ? W2 : W3;
    unsigned short* Wht = Whl + (size_t)z * 2 * DD * DD;
    unsigned short* Wlt = Wht + DD * DD;
#pragma unroll
    for (int i = 0; i < 16; ++i) {
        int idx = t + i * 256;
        int r = idx >> 6, c = idx & 63;
        tile[r][c] = W[(k0 + r) * DD + c0 + c];
    }
    __syncthreads();
#pragma unroll
    for (int i = 0; i < 16; ++i) {
        int idx = t + i * 256;
        int r = idx >> 6, c = idx & 63;
        float v = tile[c][r];
        unsigned short hi, lo;
        split2(v, hi, lo);
        Wht[(c0 + r) * DD + k0 + c] = hi;
        Wlt[(c0 + r) * DD + k0 + c] = lo;
    }
}

// ---------------- CSR build ----------------
__global__ void count_k(const int* __restrict__ ei, int* deg) {
    int e = blockIdx.x * 256 + threadIdx.x;
    if (e < EE) atomicAdd(&deg[ei[EE + e]], 1);
}

#define SCAN_T 1024
#define ITEMS 20
__global__ __launch_bounds__(SCAN_T) void scan_k(const int* __restrict__ deg, int* __restrict__ offs,
                                                 int* __restrict__ cursor, int* __restrict__ csr) {
    __shared__ int part[SCAN_T];
    int t = threadIdx.x;
    int base = t * ITEMS;
    int local[ITEMS];
    int sum = 0;
#pragma unroll
    for (int i = 0; i < ITEMS; ++i) {
        int idx = base + i;
        int v = (idx < NN) ? deg[idx] : 0;
        local[i] = v;
        sum += v;
    }
    part[t] = sum;
    __syncthreads();
    for (int s = 1; s < SCAN_T; s <<= 1) {
        int v = (t >= s) ? part[t - s] : 0;
        __syncthreads();
        part[t] += v;
        __syncthreads();
    }
    int run = (t == 0) ? 0 : part[t - 1];
#pragma unroll
    for (int i = 0; i < ITEMS; ++i) {
        int idx = base + i;
        if (idx < NN) {
            offs[idx] = run;
            cursor[idx] = run + 1;  // slot 0 of segment = self loop
            csr[run] = idx;
            run += local[i];
        }
    }
    if (t == SCAN_T - 1) offs[NN] = part[SCAN_T - 1];
}

__global__ void fill_k(const int* __restrict__ ei, int* cursor, int* __restrict__ csr) {
    int e = blockIdx.x * 256 + threadIdx.x;
    if (e < EE) {
        int s = ei[e];
        int d = ei[EE + e];
        int p = atomicAdd(&cursor[d], 1);
        csr[p] = s;
    }
}

// ---------------- MFMA GEMM + fused s,d epilogue ----------------
// 64x128 tile, 4 waves; A fragments direct from global; B staged in LDS w/ reg dbuf.
#define LDB 40
__global__ __launch_bounds__(256) void gemm_sd(const unsigned short* __restrict__ Xh,
                                               const unsigned short* __restrict__ Xl,
                                               const unsigned short* __restrict__ Bh,
                                               const unsigned short* __restrict__ Bl,
                                               const float* __restrict__ a_s,
                                               const float* __restrict__ a_d,
                                               float* __restrict__ H,
                                               float* __restrict__ sArr,
                                               float* __restrict__ dArr) {
    __shared__ unsigned short sBh[128 * LDB], sBl[128 * LDB];
    int t = threadIdx.x;
    int m0 = blockIdx.x * 64;
    int n0 = blockIdx.y * 128;
    int w = t >> 6, l = t & 63;
    int rofs = l & 15, kch = l >> 4;

    f32x4 acc[8] = {};

    int c1 = t, c2 = t + 256;
    int br1 = c1 >> 2, bo1 = (c1 & 3) * 8;
    int br2 = c2 >> 2, bo2 = (c2 & 3) * 8;
    const unsigned short* Bh1 = &Bh[(n0 + br1) * DD + bo1];
    const unsigned short* Bh2 = &Bh[(n0 + br2) * DD + bo2];
    const unsigned short* Bl1 = &Bl[(n0 + br1) * DD + bo1];
    const unsigned short* Bl2 = &Bl[(n0 + br2) * DD + bo2];
    bf8 rbh1 = *(const bf8*)Bh1;
    bf8 rbh2 = *(const bf8*)Bh2;
    bf8 rbl1 = *(const bf8*)Bl1;
    bf8 rbl2 = *(const bf8*)Bl2;

    int arow = m0 + w * 16 + rofs;
    bool aval = arow < NN;
    const unsigned short* Ahp = &Xh[(size_t)arow * DD + kch * 8];
    const unsigned short* Alp = &Xl[(size_t)arow * DD + kch * 8];
    bf8 zero = {0, 0, 0, 0, 0, 0, 0, 0};
    bf8 ah = aval ? *(const bf8*)Ahp : zero;
    bf8 al = aval ? *(const bf8*)Alp : zero;

    for (int k0 = 0; k0 < DD; k0 += 32) {
        if (k0) __syncthreads();
        *(bf8*)&sBh[br1 * LDB + bo1] = rbh1;
        *(bf8*)&sBh[br2 * LDB + bo2] = rbh2;
        *(bf8*)&sBl[br1 * LDB + bo1] = rbl1;
        *(bf8*)&sBl[br2 * LDB + bo2] = rbl2;
        __syncthreads();
        int kn = k0 + 32;
        bf8 nah = zero, nal = zero;
        if (kn < DD) {
            rbh1 = *(const bf8*)(Bh1 + kn);
            rbh2 = *(const bf8*)(Bh2 + kn);
            rbl1 = *(const bf8*)(Bl1 + kn);
            rbl2 = *(const bf8*)(Bl2 + kn);
            if (aval) {
                nah = *(const bf8*)(Ahp + kn);
                nal = *(const bf8*)(Alp + kn);
            }
        }
#pragma unroll
        for (int nt = 0; nt < 8; ++nt) {
            int r = nt * 16 + rofs;
            bf8 bh = *(const bf8*)&sBh[r * LDB + kch * 8];
            bf8 bl = *(const bf8*)&sBl[r * LDB + kch * 8];
            acc[nt] = __builtin_amdgcn_mfma_f32_16x16x32_bf16(ah, bh, acc[nt], 0, 0, 0);
            acc[nt] = __builtin_amdgcn_mfma_f32_16x16x32_bf16(ah, bl, acc[nt], 0, 0, 0);
            acc[nt] = __builtin_amdgcn_mfma_f32_16x16x32_bf16(al, bh, acc[nt], 0, 0, 0);
        }
        ah = nah;
        al = nal;
    }
    // C/D layout: col = lane&15, row = (lane>>4)*4 + reg  [m89]
    int row0 = m0 + w * 16 + (l >> 4) * 4;
    int colb = l & 15;
    float sp[4] = {0, 0, 0, 0}, dp[4] = {0, 0, 0, 0};
#pragma unroll
    for (int nt = 0; nt < 8; ++nt) {
        int cc = n0 + nt * 16 + colb;
        float vas = a_s[cc], vad = a_d[cc];
#pragma unroll
        for (int r = 0; r < 4; ++r) {
            int row = row0 + r;
            if (row < NN) H[(size_t)row * DD + cc] = acc[nt][r];
            sp[r] += acc[nt][r] * vas;
            dp[r] += acc[nt][r] * vad;
        }
    }
#pragma unroll
    for (int m = 1; m < 16; m <<= 1) {
#pragma unroll
        for (int r = 0; r < 4; ++r) {
            sp[r] += __shfl_xor(sp[r], m, 64);
            dp[r] += __shfl_xor(dp[r], m, 64);
        }
    }
    if (colb == 0) {
#pragma unroll
        for (int r = 0; r < 4; ++r) {
            int row = row0 + r;
            if (row < NN) {
                atomicAdd(&sArr[row], sp[r]);
                atomicAdd(&dArr[row], dp[r]);
            }
        }
    }
}

// ---------------- normalized edge weights: 8 threads per dst, once per edge ----------------
__global__ __launch_bounds__(256) void wnorm_k(const float* __restrict__ sArr, const float* __restrict__ dArr,
                                               const int* __restrict__ offs, const int* __restrict__ csr,
                                               float* __restrict__ wn) {
    int t = threadIdx.x;
    int sub = t & 7;
    int dst = blockIdx.x * 32 + (t >> 3);
    int beg = offs[dst], end = offs[dst + 1];
    float dd = dArr[dst];
    float den = 0.0f;
    for (int e = beg + sub; e < end; e += 8) {
        float a = sArr[csr[e]] + dd;
        a = (a > 0.0f) ? a : 0.2f * a;
        float w = __expf(a);
        wn[e] = w;
        den += w;
    }
    den += __shfl_xor(den, 1, 64);
    den += __shfl_xor(den, 2, 64);
    den += __shfl_xor(den, 4, 64);
    float inv = 1.0f / den;
    for (int e = beg + sub; e < end; e += 8) wn[e] *= inv;
}

// ---------------- strip SpMM + bias + gelu + split (pure gather) ----------------
// grid (8, 5000): blockIdx.x = 32-dim strip (XCD pin: linear%8 = strip, 2.5 MB
// H-slab per XCD L2). One WAVE per dst: lane = (eslot = l>>3, chunk = l&7).
// 8 eslots walk the edge list together; each lane loads one float4 of the strip
// row: 1 wave instr = 8 edges x 128 B = 1 KB. Weights pre-normalized in wn.
__global__ __launch_bounds__(256) void spmm_k(const float* __restrict__ H, const float* __restrict__ wn,
                                              const int* __restrict__ offs, const int* __restrict__ csr,
                                              const float* __restrict__ bias,
                                              unsigned short* __restrict__ Oh,
                                              unsigned short* __restrict__ Ol,
                                              float* __restrict__ outf32) {
    int t = threadIdx.x;
    int l = t & 63;
    int wv = t >> 6;
    int chunk = l & 7;
    int eslot = l >> 3;
    int dst = blockIdx.y * 4 + wv;
    int dim = blockIdx.x * 32 + chunk * 4;

    int beg = offs[dst], end = offs[dst + 1];
    const float* Hs = H + dim;

    float4 acc = make_float4(0, 0, 0, 0);
    for (int e = beg + eslot; e < end; e += 8) {
        int s = csr[e];
        float w = wn[e];
        const float4 h = *(const float4*)&Hs[(size_t)s * DD];
        acc.x += w * h.x;
        acc.y += w * h.y;
        acc.z += w * h.z;
        acc.w += w * h.w;
    }
#pragma unroll
    for (int m = 8; m < 64; m <<= 1) {
        acc.x += __shfl_xor(acc.x, m, 64);
        acc.y += __shfl_xor(acc.y, m, 64);
        acc.z += __shfl_xor(acc.z, m, 64);
        acc.w += __shfl_xor(acc.w, m, 64);
    }
    if (eslot == 0) {
        const float4 b = *(const float4*)&bias[dim];
        float o0 = gelu_exact(acc.x + b.x);
        float o1 = gelu_exact(acc.y + b.y);
        float o2 = gelu_exact(acc.z + b.z);
        float o3 = gelu_exact(acc.w + b.w);
        ushort4 hv, lv;
        split2(o0, hv.x, lv.x);
        split2(o1, hv.y, lv.y);
        split2(o2, hv.z, lv.z);
        split2(o3, hv.w, lv.w);
        *(ushort4*)&Oh[dst * DD + dim] = hv;
        *(ushort4*)&Ol[dst * DD + dim] = lv;
        if (outf32) {
            float4 o = make_float4(o0, o1, o2, o3);
            *(float4*)&outf32[dst * DD + dim] = o;
        }
    }
}

extern "C" void kernel_launch(void* const* d_in, const int* in_sizes, int n_in,
                              void* d_out, int out_size, void* d_ws, size_t ws_size,
                              hipStream_t stream) {
    const float* x  = (const float*)d_in[0];
    const int* ei   = (const int*)d_in[1];
    const float* W1 = (const float*)d_in[4];
    const float* as1 = (const float*)d_in[5];
    const float* ad1 = (const float*)d_in[6];
    const float* b1 = (const float*)d_in[7];
    const float* W2 = (const float*)d_in[8];
    const float* as2 = (const float*)d_in[9];
    const float* ad2 = (const float*)d_in[10];
    const float* b2 = (const float*)d_in[11];
    const float* W3 = (const float*)d_in[12];
    const float* as3 = (const float*)d_in[13];
    const float* ad3 = (const float*)d_in[14];
    const float* b3 = (const float*)d_in[15];

    float* H = (float*)d_ws;                                      // [N,256] f32
    unsigned short* Xh = (unsigned short*)(H + (size_t)NN * DD);  // [N,256] bf16
    unsigned short* Xl = Xh + (size_t)NN * DD;
    unsigned short* Whl = Xl + (size_t)NN * DD;                   // 6 x [256,256]
    float* sd = (float*)(Whl + (size_t)6 * DD * DD);              // 6*NN: s1,d1,s2,d2,s3,d3
    int* offs = (int*)(sd + (size_t)6 * NN);                      // [N+1]
    int* cursor = offs + (NN + 1);                                // [N]
    int* csr = cursor + NN;                                       // [ETOT]
    int* deg = csr + ETOT;                                        // [N]
    float* wn = (float*)(deg + NN);                               // [ETOT]

    float* sA1 = sd,           *dA1 = sd + NN;
    float* sA2 = sd + 2 * NN,  *dA2 = sd + 3 * NN;
    float* sA3 = sd + 4 * NN,  *dA3 = sd + 5 * NN;
    unsigned short* Wt1 = Whl;
    unsigned short* Wt2 = Whl + (size_t)2 * DD * DD;
    unsigned short* Wt3 = Whl + (size_t)4 * DD * DD;

    // 1: normalize+split X, zero s/d, init deg
    norm_k<<<NN / 4, 256, 0, stream>>>(x, Xh, Xl, sd, deg);
    // 2-4: CSR build
    count_k<<<(EE + 255) / 256, 256, 0, stream>>>(ei, deg);
    scan_k<<<1, SCAN_T, 0, stream>>>(deg, offs, cursor, csr);
    fill_k<<<(EE + 255) / 256, 256, 0, stream>>>(ei, cursor, csr);
    // 5: all W transposes+splits
    splitw_k<<<dim3(4, 4, 3), 256, 0, stream>>>(W1, W2, W3, Whl);

    dim3 ggrid((NN + 63) / 64, DD / 128);
    dim3 sgrid(DD / 32, NN / 4);

    // layer 1
    gemm_sd<<<ggrid, 256, 0, stream>>>(Xh, Xl, Wt1, Wt1 + DD * DD, as1, ad1, H, sA1, dA1);
    wnorm_k<<<NN / 32, 256, 0, stream>>>(sA1, dA1, offs, csr, wn);
    spmm_k<<<sgrid, 256, 0, stream>>>(H, wn, offs, csr, b1, Xh, Xl, nullptr);
    // layer 2
    gemm_sd<<<ggrid, 256, 0, stream>>>(Xh, Xl, Wt2, Wt2 + DD * DD, as2, ad2, H, sA2, dA2);
    wnorm_k<<<NN / 32, 256, 0, stream>>>(sA2, dA2, offs, csr, wn);
    spmm_k<<<sgrid, 256, 0, stream>>>(H, wn, offs, csr, b2, Xh, Xl, nullptr);
    // layer 3
    gemm_sd<<<ggrid, 256, 0, stream>>>(Xh, Xl, Wt3, Wt3 + DD * DD, as3, ad3, H, sA3, dA3);
    wnorm_k<<<NN / 32, 256, 0, stream>>>(sA3, dA3, offs, csr, wn);
    spmm_k<<<sgrid, 256, 0, stream>>>(H, wn, offs, csr, b3, Xh, Xl, (float*)d_out);
}

// Round 8
// 420.554 us; speedup vs baseline: 1.0301x; 1.0301x over previous
//
#include <hip/hip_runtime.h>
#include <math.h>

#define NN 20000
#define EE 320000
#define DD 256
#define ETOT (EE + NN)

typedef __attribute__((ext_vector_type(8))) short bf8;
typedef __attribute__((ext_vector_type(4))) float f32x4;

// exact-erf gelu via Abramowitz-Stegun 7.1.26 (|err_erf| <= 1.5e-7) with native
// rcp/exp: ~20 VALU vs ~30+ for libm erff. gelu abs err < 1e-6, budget 2.67e-5.
__device__ __forceinline__ float gelu_fast(float x) {
    float az = fabsf(x) * 0.70710678118654752f;
    float t = __builtin_amdgcn_rcpf(fmaf(0.3275911f, az, 1.0f));
    float p = fmaf(1.061405429f, t, -1.453152027f);
    p = fmaf(p, t, 1.421413741f);
    p = fmaf(p, t, -0.284496736f);
    p = fmaf(p, t, 0.254829592f);
    p = p * t;
    float e = __expf(-az * az);
    float erfa = fmaf(-p, e, 1.0f);   // erf(|x|/sqrt2)
    float erfs = copysignf(erfa, x);
    return 0.5f * x * (1.0f + erfs);
}

// round-to-nearest-even f32 -> bf16 bits
__device__ __forceinline__ unsigned short f2bf(float v) {
    unsigned u = __float_as_uint(v);
    u += 0x7fffu + ((u >> 16) & 1u);
    return (unsigned short)(u >> 16);
}
__device__ __forceinline__ float bf2f(unsigned short h) {
    return __uint_as_float(((unsigned)h) << 16);
}
__device__ __forceinline__ void split2(float v, unsigned short& hi, unsigned short& lo) {
    hi = f2bf(v);
    lo = f2bf(v - bf2f(hi));
}

// ---------------- row-normalize + split X; zero s/d buffers; init deg ----------------
__global__ __launch_bounds__(256) void norm_k(const float* __restrict__ X,
                                              unsigned short* __restrict__ Xh,
                                              unsigned short* __restrict__ Xl,
                                              float* __restrict__ sdZero,  // 6*NN floats
                                              int* __restrict__ deg) {
    int t = threadIdx.x;
    int bid = blockIdx.x;  // 0..4999
    if (t < 24) sdZero[bid * 24 + t] = 0.0f;
    if (t >= 32 && t < 36) deg[bid * 4 + (t - 32)] = 1;

    int wave = (bid * 256 + t) >> 6;
    int lane = t & 63;
    const float4 v = *(const float4*)&X[wave * DD + lane * 4];
    float ss = v.x * v.x + v.y * v.y + v.z * v.z + v.w * v.w;
    for (int off = 32; off > 0; off >>= 1) ss += __shfl_down(ss, off, 64);
    ss = __shfl(ss, 0, 64);
    float n = sqrtf(ss);
    if (n == 0.0f) n = 1e-8f;
    float inv = 1.0f / n;
    float o[4] = {v.x * inv, v.y * inv, v.z * inv, v.w * inv};
    ushort4 hv, lv;
    split2(o[0], hv.x, lv.x);
    split2(o[1], hv.y, lv.y);
    split2(o[2], hv.z, lv.z);
    split2(o[3], hv.w, lv.w);
    *(ushort4*)&Xh[wave * DD + lane * 4] = hv;
    *(ushort4*)&Xl[wave * DD + lane * 4] = lv;
}

// ---------------- W transpose + hi/lo split for all 3 layers (z = layer) ----------------
__global__ __launch_bounds__(256) void splitw_k(const float* __restrict__ W1, const float* __restrict__ W2,
                                                const float* __restrict__ W3, unsigned short* __restrict__ Whl) {
    __shared__ float tile[64][65];
    int t = threadIdx.x;
    int k0 = blockIdx.x * 64;
    int c0 = blockIdx.y * 64;
    int z = blockIdx.z;
    const float* W = (z == 0) ? W1 : (z == 1) ? W2 : W3;
    unsigned short* Wht = Whl + (size_t)z * 2 * DD * DD;
    unsigned short* Wlt = Wht + DD * DD;
#pragma unroll
    for (int i = 0; i < 16; ++i) {
        int idx = t + i * 256;
        int r = idx >> 6, c = idx & 63;
        tile[r][c] = W[(k0 + r) * DD + c0 + c];
    }
    __syncthreads();
#pragma unroll
    for (int i = 0; i < 16; ++i) {
        int idx = t + i * 256;
        int r = idx >> 6, c = idx & 63;
        float v = tile[c][r];
        unsigned short hi, lo;
        split2(v, hi, lo);
        Wht[(c0 + r) * DD + k0 + c] = hi;
        Wlt[(c0 + r) * DD + k0 + c] = lo;
    }
}

// ---------------- CSR build ----------------
__global__ void count_k(const int* __restrict__ ei, int* deg) {
    int e = blockIdx.x * 256 + threadIdx.x;
    if (e < EE) atomicAdd(&deg[ei[EE + e]], 1);
}

#define SCAN_T 1024
#define ITEMS 20
__global__ __launch_bounds__(SCAN_T) void scan_k(const int* __restrict__ deg, int* __restrict__ offs,
                                                 int* __restrict__ cursor, int* __restrict__ csr) {
    __shared__ int part[SCAN_T];
    int t = threadIdx.x;
    int base = t * ITEMS;
    int local[ITEMS];
    int sum = 0;
#pragma unroll
    for (int i = 0; i < ITEMS; ++i) {
        int idx = base + i;
        int v = (idx < NN) ? deg[idx] : 0;
        local[i] = v;
        sum += v;
    }
    part[t] = sum;
    __syncthreads();
    for (int s = 1; s < SCAN_T; s <<= 1) {
        int v = (t >= s) ? part[t - s] : 0;
        __syncthreads();
        part[t] += v;
        __syncthreads();
    }
    int run = (t == 0) ? 0 : part[t - 1];
#pragma unroll
    for (int i = 0; i < ITEMS; ++i) {
        int idx = base + i;
        if (idx < NN) {
            offs[idx] = run;
            cursor[idx] = run + 1;  // slot 0 of segment = self loop
            csr[run] = idx;
            run += local[i];
        }
    }
    if (t == SCAN_T - 1) offs[NN] = part[SCAN_T - 1];
}

__global__ void fill_k(const int* __restrict__ ei, int* cursor, int* __restrict__ csr) {
    int e = blockIdx.x * 256 + threadIdx.x;
    if (e < EE) {
        int s = ei[e];
        int d = ei[EE + e];
        int p = atomicAdd(&cursor[d], 1);
        csr[p] = s;
    }
}

// ---------------- MFMA GEMM + fused s,d epilogue ----------------
// 64x128 tile, 4 waves; A fragments direct from global; B staged in LDS w/ reg dbuf.
#define LDB 40
__global__ __launch_bounds__(256) void gemm_sd(const unsigned short* __restrict__ Xh,
                                               const unsigned short* __restrict__ Xl,
                                               const unsigned short* __restrict__ Bh,
                                               const unsigned short* __restrict__ Bl,
                                               const float* __restrict__ a_s,
                                               const float* __restrict__ a_d,
                                               float* __restrict__ H,
                                               float* __restrict__ sArr,
                                               float* __restrict__ dArr) {
    __shared__ unsigned short sBh[128 * LDB], sBl[128 * LDB];
    int t = threadIdx.x;
    int m0 = blockIdx.x * 64;
    int n0 = blockIdx.y * 128;
    int w = t >> 6, l = t & 63;
    int rofs = l & 15, kch = l >> 4;

    f32x4 acc[8] = {};

    int c1 = t, c2 = t + 256;
    int br1 = c1 >> 2, bo1 = (c1 & 3) * 8;
    int br2 = c2 >> 2, bo2 = (c2 & 3) * 8;
    const unsigned short* Bh1 = &Bh[(n0 + br1) * DD + bo1];
    const unsigned short* Bh2 = &Bh[(n0 + br2) * DD + bo2];
    const unsigned short* Bl1 = &Bl[(n0 + br1) * DD + bo1];
    const unsigned short* Bl2 = &Bl[(n0 + br2) * DD + bo2];
    bf8 rbh1 = *(const bf8*)Bh1;
    bf8 rbh2 = *(const bf8*)Bh2;
    bf8 rbl1 = *(const bf8*)Bl1;
    bf8 rbl2 = *(const bf8*)Bl2;

    int arow = m0 + w * 16 + rofs;
    bool aval = arow < NN;
    const unsigned short* Ahp = &Xh[(size_t)arow * DD + kch * 8];
    const unsigned short* Alp = &Xl[(size_t)arow * DD + kch * 8];
    bf8 zero = {0, 0, 0, 0, 0, 0, 0, 0};
    bf8 ah = aval ? *(const bf8*)Ahp : zero;
    bf8 al = aval ? *(const bf8*)Alp : zero;

    for (int k0 = 0; k0 < DD; k0 += 32) {
        if (k0) __syncthreads();
        *(bf8*)&sBh[br1 * LDB + bo1] = rbh1;
        *(bf8*)&sBh[br2 * LDB + bo2] = rbh2;
        *(bf8*)&sBl[br1 * LDB + bo1] = rbl1;
        *(bf8*)&sBl[br2 * LDB + bo2] = rbl2;
        __syncthreads();
        int kn = k0 + 32;
        bf8 nah = zero, nal = zero;
        if (kn < DD) {
            rbh1 = *(const bf8*)(Bh1 + kn);
            rbh2 = *(const bf8*)(Bh2 + kn);
            rbl1 = *(const bf8*)(Bl1 + kn);
            rbl2 = *(const bf8*)(Bl2 + kn);
            if (aval) {
                nah = *(const bf8*)(Ahp + kn);
                nal = *(const bf8*)(Alp + kn);
            }
        }
#pragma unroll
        for (int nt = 0; nt < 8; ++nt) {
            int r = nt * 16 + rofs;
            bf8 bh = *(const bf8*)&sBh[r * LDB + kch * 8];
            bf8 bl = *(const bf8*)&sBl[r * LDB + kch * 8];
            acc[nt] = __builtin_amdgcn_mfma_f32_16x16x32_bf16(ah, bh, acc[nt], 0, 0, 0);
            acc[nt] = __builtin_amdgcn_mfma_f32_16x16x32_bf16(ah, bl, acc[nt], 0, 0, 0);
            acc[nt] = __builtin_amdgcn_mfma_f32_16x16x32_bf16(al, bh, acc[nt], 0, 0, 0);
        }
        ah = nah;
        al = nal;
    }
    // C/D layout: col = lane&15, row = (lane>>4)*4 + reg  [m89]
    int row0 = m0 + w * 16 + (l >> 4) * 4;
    int colb = l & 15;
    float sp[4] = {0, 0, 0, 0}, dp[4] = {0, 0, 0, 0};
#pragma unroll
    for (int nt = 0; nt < 8; ++nt) {
        int cc = n0 + nt * 16 + colb;
        float vas = a_s[cc], vad = a_d[cc];
#pragma unroll
        for (int r = 0; r < 4; ++r) {
            int row = row0 + r;
            if (row < NN) H[(size_t)row * DD + cc] = acc[nt][r];
            sp[r] += acc[nt][r] * vas;
            dp[r] += acc[nt][r] * vad;
        }
    }
#pragma unroll
    for (int m = 1; m < 16; m <<= 1) {
#pragma unroll
        for (int r = 0; r < 4; ++r) {
            sp[r] += __shfl_xor(sp[r], m, 64);
            dp[r] += __shfl_xor(dp[r], m, 64);
        }
    }
    if (colb == 0) {
#pragma unroll
        for (int r = 0; r < 4; ++r) {
            int row = row0 + r;
            if (row < NN) {
                atomicAdd(&sArr[row], sp[r]);
                atomicAdd(&dArr[row], dp[r]);
            }
        }
    }
}

// ---------------- normalized edge weights: 8 threads per dst, once per edge ----------------
__global__ __launch_bounds__(256) void wnorm_k(const float* __restrict__ sArr, const float* __restrict__ dArr,
                                               const int* __restrict__ offs, const int* __restrict__ csr,
                                               float* __restrict__ wn) {
    int t = threadIdx.x;
    int sub = t & 7;
    int dst = blockIdx.x * 32 + (t >> 3);
    int beg = offs[dst], end = offs[dst + 1];
    float dd = dArr[dst];
    float den = 0.0f;
    for (int e = beg + sub; e < end; e += 8) {
        float a = sArr[csr[e]] + dd;
        a = (a > 0.0f) ? a : 0.2f * a;
        float w = __expf(a);
        wn[e] = w;
        den += w;
    }
    den += __shfl_xor(den, 1, 64);
    den += __shfl_xor(den, 2, 64);
    den += __shfl_xor(den, 4, 64);
    float inv = 1.0f / den;
    for (int e = beg + sub; e < end; e += 8) wn[e] *= inv;
}

// ---------------- strip SpMM + bias + gelu + split (pure gather) ----------------
// grid (8, 5000): blockIdx.x = 32-dim strip (XCD pin: linear%8 = strip, 2.5 MB
// H-slab per XCD L2). One WAVE per dst: lane = (eslot = l>>3, chunk = l&7).
// 8 eslots walk the edge list together; each lane loads one float4 of the strip
// row: 1 wave instr = 8 edges x 128 B. Epilogue: redistribute so EVERY lane
// computes one scalar gelu (one gelu sequence per wave, full lane utilization),
// then coalesced scalar stores from lanes 0..31.
__global__ __launch_bounds__(256) void spmm_k(const float* __restrict__ H, const float* __restrict__ wn,
                                              const int* __restrict__ offs, const int* __restrict__ csr,
                                              const float* __restrict__ bias,
                                              unsigned short* __restrict__ Oh,
                                              unsigned short* __restrict__ Ol,
                                              float* __restrict__ outf32) {
    int t = threadIdx.x;
    int l = t & 63;
    int wv = t >> 6;
    int chunk = l & 7;
    int eslot = l >> 3;
    int dst = blockIdx.y * 4 + wv;
    int dim = blockIdx.x * 32 + chunk * 4;

    int beg = offs[dst], end = offs[dst + 1];
    const float* Hs = H + dim;

    float4 acc = make_float4(0, 0, 0, 0);
    for (int e = beg + eslot; e < end; e += 8) {
        int s = csr[e];
        float w = wn[e];
        const float4 h = *(const float4*)&Hs[(size_t)s * DD];
        acc.x += w * h.x;
        acc.y += w * h.y;
        acc.z += w * h.z;
        acc.w += w * h.w;
    }
#pragma unroll
    for (int m = 8; m < 64; m <<= 1) {
        acc.x += __shfl_xor(acc.x, m, 64);
        acc.y += __shfl_xor(acc.y, m, 64);
        acc.z += __shfl_xor(acc.z, m, 64);
        acc.w += __shfl_xor(acc.w, m, 64);
    }
    // redistribute: lane j<32 -> scalar dim strip*32 + j (chunk j>>2, elem j&3)
    int j = l & 31;
    int srcLane = j >> 2;  // lane holding chunk j>>2 (its chunk == lane&7 for lanes 0..7)
    float vx = __shfl(acc.x, srcLane, 64);
    float vy = __shfl(acc.y, srcLane, 64);
    float vz = __shfl(acc.z, srcLane, 64);
    float vw = __shfl(acc.w, srcLane, 64);
    int r = j & 3;
    float v = (r == 0) ? vx : (r == 1) ? vy : (r == 2) ? vz : vw;
    int dimj = blockIdx.x * 32 + j;
    v += bias[dimj];
    float g = gelu_fast(v);
    unsigned short hi, lo;
    split2(g, hi, lo);
    if (l < 32) {
        Oh[dst * DD + dimj] = hi;
        Ol[dst * DD + dimj] = lo;
        if (outf32) outf32[dst * DD + dimj] = g;
    }
}

extern "C" void kernel_launch(void* const* d_in, const int* in_sizes, int n_in,
                              void* d_out, int out_size, void* d_ws, size_t ws_size,
                              hipStream_t stream) {
    const float* x  = (const float*)d_in[0];
    const int* ei   = (const int*)d_in[1];
    const float* W1 = (const float*)d_in[4];
    const float* as1 = (const float*)d_in[5];
    const float* ad1 = (const float*)d_in[6];
    const float* b1 = (const float*)d_in[7];
    const float* W2 = (const float*)d_in[8];
    const float* as2 = (const float*)d_in[9];
    const float* ad2 = (const float*)d_in[10];
    const float* b2 = (const float*)d_in[11];
    const float* W3 = (const float*)d_in[12];
    const float* as3 = (const float*)d_in[13];
    const float* ad3 = (const float*)d_in[14];
    const float* b3 = (const float*)d_in[15];

    float* H = (float*)d_ws;                                      // [N,256] f32
    unsigned short* Xh = (unsigned short*)(H + (size_t)NN * DD);  // [N,256] bf16
    unsigned short* Xl = Xh + (size_t)NN * DD;
    unsigned short* Whl = Xl + (size_t)NN * DD;                   // 6 x [256,256]
    float* sd = (float*)(Whl + (size_t)6 * DD * DD);              // 6*NN: s1,d1,s2,d2,s3,d3
    int* offs = (int*)(sd + (size_t)6 * NN);                      // [N+1]
    int* cursor = offs + (NN + 1);                                // [N]
    int* csr = cursor + NN;                                       // [ETOT]
    int* deg = csr + ETOT;                                        // [N]
    float* wn = (float*)(deg + NN);                               // [ETOT]

    float* sA1 = sd,           *dA1 = sd + NN;
    float* sA2 = sd + 2 * NN,  *dA2 = sd + 3 * NN;
    float* sA3 = sd + 4 * NN,  *dA3 = sd + 5 * NN;
    unsigned short* Wt1 = Whl;
    unsigned short* Wt2 = Whl + (size_t)2 * DD * DD;
    unsigned short* Wt3 = Whl + (size_t)4 * DD * DD;

    // 1: normalize+split X, zero s/d, init deg
    norm_k<<<NN / 4, 256, 0, stream>>>(x, Xh, Xl, sd, deg);
    // 2-4: CSR build
    count_k<<<(EE + 255) / 256, 256, 0, stream>>>(ei, deg);
    scan_k<<<1, SCAN_T, 0, stream>>>(deg, offs, cursor, csr);
    fill_k<<<(EE + 255) / 256, 256, 0, stream>>>(ei, cursor, csr);
    // 5: all W transposes+splits
    splitw_k<<<dim3(4, 4, 3), 256, 0, stream>>>(W1, W2, W3, Whl);

    dim3 ggrid((NN + 63) / 64, DD / 128);
    dim3 sgrid(DD / 32, NN / 4);

    // layer 1
    gemm_sd<<<ggrid, 256, 0, stream>>>(Xh, Xl, Wt1, Wt1 + DD * DD, as1, ad1, H, sA1, dA1);
    wnorm_k<<<NN / 32, 256, 0, stream>>>(sA1, dA1, offs, csr, wn);
    spmm_k<<<sgrid, 256, 0, stream>>>(H, wn, offs, csr, b1, Xh, Xl, nullptr);
    // layer 2
    gemm_sd<<<ggrid, 256, 0, stream>>>(Xh, Xl, Wt2, Wt2 + DD * DD, as2, ad2, H, sA2, dA2);
    wnorm_k<<<NN / 32, 256, 0, stream>>>(sA2, dA2, offs, csr, wn);
    spmm_k<<<sgrid, 256, 0, stream>>>(H, wn, offs, csr, b2, Xh, Xl, nullptr);
    // layer 3
    gemm_sd<<<ggrid, 256, 0, stream>>>(Xh, Xl, Wt3, Wt3 + DD * DD, as3, ad3, H, sA3, dA3);
    wnorm_k<<<NN / 32, 256, 0, stream>>>(sA3, dA3, offs, csr, wn);
    spmm_k<<<sgrid, 256, 0, stream>>>(H, wn, offs, csr, b3, Xh, Xl, (float*)d_out);
}

// Round 9
// 419.189 us; speedup vs baseline: 1.0335x; 1.0033x over previous
//
#include <hip/hip_runtime.h>
#include <math.h>

#define NN 20000
#define EE 320000
#define DD 256
#define ETOT (EE + NN)

typedef __attribute__((ext_vector_type(8))) short bf8;
typedef __attribute__((ext_vector_type(4))) float f32x4;

// exact-erf gelu via Abramowitz-Stegun 7.1.26 (|err_erf| <= 1.5e-7) with native
// rcp/exp. gelu abs err < 1e-6, budget 2.67e-5.
__device__ __forceinline__ float gelu_fast(float x) {
    float az = fabsf(x) * 0.70710678118654752f;
    float t = __builtin_amdgcn_rcpf(fmaf(0.3275911f, az, 1.0f));
    float p = fmaf(1.061405429f, t, -1.453152027f);
    p = fmaf(p, t, 1.421413741f);
    p = fmaf(p, t, -0.284496736f);
    p = fmaf(p, t, 0.254829592f);
    p = p * t;
    float e = __expf(-az * az);
    float erfa = fmaf(-p, e, 1.0f);   // erf(|x|/sqrt2)
    float erfs = copysignf(erfa, x);
    return 0.5f * x * (1.0f + erfs);
}

// round-to-nearest-even f32 -> bf16 bits
__device__ __forceinline__ unsigned short f2bf(float v) {
    unsigned u = __float_as_uint(v);
    u += 0x7fffu + ((u >> 16) & 1u);
    return (unsigned short)(u >> 16);
}
__device__ __forceinline__ float bf2f(unsigned short h) {
    return __uint_as_float(((unsigned)h) << 16);
}
__device__ __forceinline__ void split2(float v, unsigned short& hi, unsigned short& lo) {
    hi = f2bf(v);
    lo = f2bf(v - bf2f(hi));
}

// argument-free xor-lane-swizzle add helpers (BitMode: offset=(xor<<10)|0x1F)
__device__ __forceinline__ float swz_xor1(float v) {
    return __int_as_float(__builtin_amdgcn_ds_swizzle(__float_as_int(v), 0x041F));
}
__device__ __forceinline__ float swz_xor2(float v) {
    return __int_as_float(__builtin_amdgcn_ds_swizzle(__float_as_int(v), 0x081F));
}

// ---------------- row-normalize + split X; zero s/d buffers; init deg ----------------
__global__ __launch_bounds__(256) void norm_k(const float* __restrict__ X,
                                              unsigned short* __restrict__ Xh,
                                              unsigned short* __restrict__ Xl,
                                              float* __restrict__ sdZero,  // 6*NN floats
                                              int* __restrict__ deg) {
    int t = threadIdx.x;
    int bid = blockIdx.x;  // 0..4999
    if (t < 24) sdZero[bid * 24 + t] = 0.0f;
    if (t >= 32 && t < 36) deg[bid * 4 + (t - 32)] = 1;

    int wave = (bid * 256 + t) >> 6;
    int lane = t & 63;
    const float4 v = *(const float4*)&X[wave * DD + lane * 4];
    float ss = v.x * v.x + v.y * v.y + v.z * v.z + v.w * v.w;
    for (int off = 32; off > 0; off >>= 1) ss += __shfl_down(ss, off, 64);
    ss = __shfl(ss, 0, 64);
    float n = sqrtf(ss);
    if (n == 0.0f) n = 1e-8f;
    float inv = 1.0f / n;
    float o[4] = {v.x * inv, v.y * inv, v.z * inv, v.w * inv};
    ushort4 hv, lv;
    split2(o[0], hv.x, lv.x);
    split2(o[1], hv.y, lv.y);
    split2(o[2], hv.z, lv.z);
    split2(o[3], hv.w, lv.w);
    *(ushort4*)&Xh[wave * DD + lane * 4] = hv;
    *(ushort4*)&Xl[wave * DD + lane * 4] = lv;
}

// ---------------- W transpose + hi/lo split for all 3 layers (z = layer) ----------------
__global__ __launch_bounds__(256) void splitw_k(const float* __restrict__ W1, const float* __restrict__ W2,
                                                const float* __restrict__ W3, unsigned short* __restrict__ Whl) {
    __shared__ float tile[64][65];
    int t = threadIdx.x;
    int k0 = blockIdx.x * 64;
    int c0 = blockIdx.y * 64;
    int z = blockIdx.z;
    const float* W = (z == 0) ? W1 : (z == 1) ? W2 : W3;
    unsigned short* Wht = Whl + (size_t)z * 2 * DD * DD;
    unsigned short* Wlt = Wht + DD * DD;
#pragma unroll
    for (int i = 0; i < 16; ++i) {
        int idx = t + i * 256;
        int r = idx >> 6, c = idx & 63;
        tile[r][c] = W[(k0 + r) * DD + c0 + c];
    }
    __syncthreads();
#pragma unroll
    for (int i = 0; i < 16; ++i) {
        int idx = t + i * 256;
        int r = idx >> 6, c = idx & 63;
        float v = tile[c][r];
        unsigned short hi, lo;
        split2(v, hi, lo);
        Wht[(c0 + r) * DD + k0 + c] = hi;
        Wlt[(c0 + r) * DD + k0 + c] = lo;
    }
}

// ---------------- CSR build ----------------
__global__ void count_k(const int* __restrict__ ei, int* deg) {
    int e = blockIdx.x * 256 + threadIdx.x;
    if (e < EE) atomicAdd(&deg[ei[EE + e]], 1);
}

#define SCAN_T 1024
#define ITEMS 20
__global__ __launch_bounds__(SCAN_T) void scan_k(const int* __restrict__ deg, int* __restrict__ offs,
                                                 int* __restrict__ cursor, int* __restrict__ csr) {
    __shared__ int part[SCAN_T];
    int t = threadIdx.x;
    int base = t * ITEMS;
    int local[ITEMS];
    int sum = 0;
#pragma unroll
    for (int i = 0; i < ITEMS; ++i) {
        int idx = base + i;
        int v = (idx < NN) ? deg[idx] : 0;
        local[i] = v;
        sum += v;
    }
    part[t] = sum;
    __syncthreads();
    for (int s = 1; s < SCAN_T; s <<= 1) {
        int v = (t >= s) ? part[t - s] : 0;
        __syncthreads();
        part[t] += v;
        __syncthreads();
    }
    int run = (t == 0) ? 0 : part[t - 1];
#pragma unroll
    for (int i = 0; i < ITEMS; ++i) {
        int idx = base + i;
        if (idx < NN) {
            offs[idx] = run;
            cursor[idx] = run + 1;  // slot 0 of segment = self loop
            csr[run] = idx;
            run += local[i];
        }
    }
    if (t == SCAN_T - 1) offs[NN] = part[SCAN_T - 1];
}

__global__ void fill_k(const int* __restrict__ ei, int* cursor, int* __restrict__ csr) {
    int e = blockIdx.x * 256 + threadIdx.x;
    if (e < EE) {
        int s = ei[e];
        int d = ei[EE + e];
        int p = atomicAdd(&cursor[d], 1);
        csr[p] = s;
    }
}

// ---------------- MFMA GEMM + fused s,d epilogue ----------------
// 64x128 tile, 4 waves; A fragments direct from global; B staged in LDS w/ reg dbuf.
#define LDB 40
__global__ __launch_bounds__(256) void gemm_sd(const unsigned short* __restrict__ Xh,
                                               const unsigned short* __restrict__ Xl,
                                               const unsigned short* __restrict__ Bh,
                                               const unsigned short* __restrict__ Bl,
                                               const float* __restrict__ a_s,
                                               const float* __restrict__ a_d,
                                               float* __restrict__ H,
                                               float* __restrict__ sArr,
                                               float* __restrict__ dArr) {
    __shared__ unsigned short sBh[128 * LDB], sBl[128 * LDB];
    int t = threadIdx.x;
    int m0 = blockIdx.x * 64;
    int n0 = blockIdx.y * 128;
    int w = t >> 6, l = t & 63;
    int rofs = l & 15, kch = l >> 4;

    f32x4 acc[8] = {};

    int c1 = t, c2 = t + 256;
    int br1 = c1 >> 2, bo1 = (c1 & 3) * 8;
    int br2 = c2 >> 2, bo2 = (c2 & 3) * 8;
    const unsigned short* Bh1 = &Bh[(n0 + br1) * DD + bo1];
    const unsigned short* Bh2 = &Bh[(n0 + br2) * DD + bo2];
    const unsigned short* Bl1 = &Bl[(n0 + br1) * DD + bo1];
    const unsigned short* Bl2 = &Bl[(n0 + br2) * DD + bo2];
    bf8 rbh1 = *(const bf8*)Bh1;
    bf8 rbh2 = *(const bf8*)Bh2;
    bf8 rbl1 = *(const bf8*)Bl1;
    bf8 rbl2 = *(const bf8*)Bl2;

    int arow = m0 + w * 16 + rofs;
    bool aval = arow < NN;
    const unsigned short* Ahp = &Xh[(size_t)arow * DD + kch * 8];
    const unsigned short* Alp = &Xl[(size_t)arow * DD + kch * 8];
    bf8 zero = {0, 0, 0, 0, 0, 0, 0, 0};
    bf8 ah = aval ? *(const bf8*)Ahp : zero;
    bf8 al = aval ? *(const bf8*)Alp : zero;

    for (int k0 = 0; k0 < DD; k0 += 32) {
        if (k0) __syncthreads();
        *(bf8*)&sBh[br1 * LDB + bo1] = rbh1;
        *(bf8*)&sBh[br2 * LDB + bo2] = rbh2;
        *(bf8*)&sBl[br1 * LDB + bo1] = rbl1;
        *(bf8*)&sBl[br2 * LDB + bo2] = rbl2;
        __syncthreads();
        int kn = k0 + 32;
        bf8 nah = zero, nal = zero;
        if (kn < DD) {
            rbh1 = *(const bf8*)(Bh1 + kn);
            rbh2 = *(const bf8*)(Bh2 + kn);
            rbl1 = *(const bf8*)(Bl1 + kn);
            rbl2 = *(const bf8*)(Bl2 + kn);
            if (aval) {
                nah = *(const bf8*)(Ahp + kn);
                nal = *(const bf8*)(Alp + kn);
            }
        }
#pragma unroll
        for (int nt = 0; nt < 8; ++nt) {
            int r = nt * 16 + rofs;
            bf8 bh = *(const bf8*)&sBh[r * LDB + kch * 8];
            bf8 bl = *(const bf8*)&sBl[r * LDB + kch * 8];
            acc[nt] = __builtin_amdgcn_mfma_f32_16x16x32_bf16(ah, bh, acc[nt], 0, 0, 0);
            acc[nt] = __builtin_amdgcn_mfma_f32_16x16x32_bf16(ah, bl, acc[nt], 0, 0, 0);
            acc[nt] = __builtin_amdgcn_mfma_f32_16x16x32_bf16(al, bh, acc[nt], 0, 0, 0);
        }
        ah = nah;
        al = nal;
    }
    // C/D layout: col = lane&15, row = (lane>>4)*4 + reg  [m89]
    int row0 = m0 + w * 16 + (l >> 4) * 4;
    int colb = l & 15;
    float sp[4] = {0, 0, 0, 0}, dp[4] = {0, 0, 0, 0};
#pragma unroll
    for (int nt = 0; nt < 8; ++nt) {
        int cc = n0 + nt * 16 + colb;
        float vas = a_s[cc], vad = a_d[cc];
#pragma unroll
        for (int r = 0; r < 4; ++r) {
            int row = row0 + r;
            if (row < NN) H[(size_t)row * DD + cc] = acc[nt][r];
            sp[r] += acc[nt][r] * vas;
            dp[r] += acc[nt][r] * vad;
        }
    }
#pragma unroll
    for (int m = 1; m < 16; m <<= 1) {
#pragma unroll
        for (int r = 0; r < 4; ++r) {
            sp[r] += __shfl_xor(sp[r], m, 64);
            dp[r] += __shfl_xor(dp[r], m, 64);
        }
    }
    if (colb == 0) {
#pragma unroll
        for (int r = 0; r < 4; ++r) {
            int row = row0 + r;
            if (row < NN) {
                atomicAdd(&sArr[row], sp[r]);
                atomicAdd(&dArr[row], dp[r]);
            }
        }
    }
}

// ---------------- normalized edge weights -> packed {src, w} pairs ----------------
__global__ __launch_bounds__(256) void wnorm_k(const float* __restrict__ sArr, const float* __restrict__ dArr,
                                               const int* __restrict__ offs, const int* __restrict__ csr,
                                               int2* __restrict__ ewn) {
    int t = threadIdx.x;
    int sub = t & 7;
    int dst = blockIdx.x * 32 + (t >> 3);
    int beg = offs[dst], end = offs[dst + 1];
    float dd = dArr[dst];
    float den = 0.0f;
    for (int e = beg + sub; e < end; e += 8) {
        int s = csr[e];
        float a = sArr[s] + dd;
        a = (a > 0.0f) ? a : 0.2f * a;
        float w = __expf(a);
        ewn[e] = make_int2(s, __float_as_int(w));
        den += w;
    }
    den += __shfl_xor(den, 1, 64);
    den += __shfl_xor(den, 2, 64);
    den += __shfl_xor(den, 4, 64);
    float inv = 1.0f / den;
    float* wp = (float*)ewn;
    for (int e = beg + sub; e < end; e += 8) wp[2 * e + 1] *= inv;
}

// ---------------- strip SpMM + bias + gelu + split ----------------
// grid (4, 5000): blockIdx.x = 64-dim strip (5 MB slab pinned to XCD pair
// {s, s+4} under linear%8). One WAVE per dst; lane = (chunk = l>>2, eslot = l&3):
// 4 eslots walk the edge list together, each lane loads one float4 of the strip
// row (64 lanes x 16 B = 1 KB). eslot lives in the LOW lane bits so the reduce
// is xor-1/xor-2 ds_swizzle (no bpermute addr setup) AND after it lane j already
// holds the sum for dim j's quad -- zero-shuffle redistribute, just a component
// select. One gelu per lane, fully coalesced 2-B/4-B stores.
__global__ __launch_bounds__(256) void spmm_k(const float* __restrict__ H, const int2* __restrict__ ewn,
                                              const int* __restrict__ offs, const float* __restrict__ bias,
                                              unsigned short* __restrict__ Oh,
                                              unsigned short* __restrict__ Ol,
                                              float* __restrict__ outf32) {
    int t = threadIdx.x;
    int l = t & 63;
    int wv = t >> 6;
    int eslot = l & 3;
    int chunk = l >> 2;
    int dst = blockIdx.y * 4 + wv;
    int dim0 = blockIdx.x * 64;

    int beg = offs[dst], end = offs[dst + 1];
    const float* Hs = H + dim0 + chunk * 4;

    float ax = 0, ay = 0, az = 0, aw = 0;
    int e = beg + eslot;
    for (; e + 4 < end; e += 8) {
        int2 p0 = ewn[e];
        int2 p1 = ewn[e + 4];
        float w0 = __int_as_float(p0.y);
        float w1 = __int_as_float(p1.y);
        const float4 h0 = *(const float4*)&Hs[(size_t)p0.x * DD];
        const float4 h1 = *(const float4*)&Hs[(size_t)p1.x * DD];
        ax += w0 * h0.x; ay += w0 * h0.y; az += w0 * h0.z; aw += w0 * h0.w;
        ax += w1 * h1.x; ay += w1 * h1.y; az += w1 * h1.z; aw += w1 * h1.w;
    }
    if (e < end) {
        int2 p0 = ewn[e];
        float w0 = __int_as_float(p0.y);
        const float4 h0 = *(const float4*)&Hs[(size_t)p0.x * DD];
        ax += w0 * h0.x; ay += w0 * h0.y; az += w0 * h0.z; aw += w0 * h0.w;
    }
    // reduce over the 4 eslots within each quad (xor-1, xor-2 swizzles)
    ax += swz_xor1(ax); ay += swz_xor1(ay); az += swz_xor1(az); aw += swz_xor1(aw);
    ax += swz_xor2(ax); ay += swz_xor2(ay); az += swz_xor2(az); aw += swz_xor2(aw);
    // lane j now holds the reduced quad (j>>2); dim j is component j&3
    float v = (eslot == 0) ? ax : (eslot == 1) ? ay : (eslot == 2) ? az : aw;
    int dimj = dim0 + l;
    v += bias[dimj];
    float g = gelu_fast(v);
    unsigned short hi, lo;
    split2(g, hi, lo);
    Oh[dst * DD + dimj] = hi;
    Ol[dst * DD + dimj] = lo;
    if (outf32) outf32[dst * DD + dimj] = g;
}

extern "C" void kernel_launch(void* const* d_in, const int* in_sizes, int n_in,
                              void* d_out, int out_size, void* d_ws, size_t ws_size,
                              hipStream_t stream) {
    const float* x  = (const float*)d_in[0];
    const int* ei   = (const int*)d_in[1];
    const float* W1 = (const float*)d_in[4];
    const float* as1 = (const float*)d_in[5];
    const float* ad1 = (const float*)d_in[6];
    const float* b1 = (const float*)d_in[7];
    const float* W2 = (const float*)d_in[8];
    const float* as2 = (const float*)d_in[9];
    const float* ad2 = (const float*)d_in[10];
    const float* b2 = (const float*)d_in[11];
    const float* W3 = (const float*)d_in[12];
    const float* as3 = (const float*)d_in[13];
    const float* ad3 = (const float*)d_in[14];
    const float* b3 = (const float*)d_in[15];

    float* H = (float*)d_ws;                                      // [N,256] f32
    unsigned short* Xh = (unsigned short*)(H + (size_t)NN * DD);  // [N,256] bf16
    unsigned short* Xl = Xh + (size_t)NN * DD;
    unsigned short* Whl = Xl + (size_t)NN * DD;                   // 6 x [256,256]
    float* sd = (float*)(Whl + (size_t)6 * DD * DD);              // 6*NN: s1,d1,s2,d2,s3,d3
    int* offs = (int*)(sd + (size_t)6 * NN);                      // [N+1]
    int* cursor = offs + (NN + 1);                                // [N]
    int* csr = cursor + NN;                                       // [ETOT]
    int* deg = csr + ETOT;                                        // [N]
    int2* ewn = (int2*)(deg + NN);                                // [ETOT] {src, w}

    float* sA1 = sd,           *dA1 = sd + NN;
    float* sA2 = sd + 2 * NN,  *dA2 = sd + 3 * NN;
    float* sA3 = sd + 4 * NN,  *dA3 = sd + 5 * NN;
    unsigned short* Wt1 = Whl;
    unsigned short* Wt2 = Whl + (size_t)2 * DD * DD;
    unsigned short* Wt3 = Whl + (size_t)4 * DD * DD;

    // 1: normalize+split X, zero s/d, init deg
    norm_k<<<NN / 4, 256, 0, stream>>>(x, Xh, Xl, sd, deg);
    // 2-4: CSR build
    count_k<<<(EE + 255) / 256, 256, 0, stream>>>(ei, deg);
    scan_k<<<1, SCAN_T, 0, stream>>>(deg, offs, cursor, csr);
    fill_k<<<(EE + 255) / 256, 256, 0, stream>>>(ei, cursor, csr);
    // 5: all W transposes+splits
    splitw_k<<<dim3(4, 4, 3), 256, 0, stream>>>(W1, W2, W3, Whl);

    dim3 ggrid((NN + 63) / 64, DD / 128);
    dim3 sgrid(DD / 64, NN / 4);

    // layer 1
    gemm_sd<<<ggrid, 256, 0, stream>>>(Xh, Xl, Wt1, Wt1 + DD * DD, as1, ad1, H, sA1, dA1);
    wnorm_k<<<NN / 32, 256, 0, stream>>>(sA1, dA1, offs, csr, ewn);
    spmm_k<<<sgrid, 256, 0, stream>>>(H, ewn, offs, b1, Xh, Xl, nullptr);
    // layer 2
    gemm_sd<<<ggrid, 256, 0, stream>>>(Xh, Xl, Wt2, Wt2 + DD * DD, as2, ad2, H, sA2, dA2);
    wnorm_k<<<NN / 32, 256, 0, stream>>>(sA2, dA2, offs, csr, ewn);
    spmm_k<<<sgrid, 256, 0, stream>>>(H, ewn, offs, b2, Xh, Xl, nullptr);
    // layer 3
    gemm_sd<<<ggrid, 256, 0, stream>>>(Xh, Xl, Wt3, Wt3 + DD * DD, as3, ad3, H, sA3, dA3);
    wnorm_k<<<NN / 32, 256, 0, stream>>>(sA3, dA3, offs, csr, ewn);
    spmm_k<<<sgrid, 256, 0, stream>>>(H, ewn, offs, b3, Xh, Xl, (float*)d_out);
}

// Round 10
// 360.681 us; speedup vs baseline: 1.2011x; 1.1622x over previous
//
#include <hip/hip_runtime.h>
#include <math.h>

#define NN 20000
#define EE 320000
#define DD 256
#define ETOT (EE + NN)

typedef __attribute__((ext_vector_type(8))) short bf8;
typedef __attribute__((ext_vector_type(4))) float f32x4;

// exact-erf gelu via Abramowitz-Stegun 7.1.26 (|err_erf| <= 1.5e-7) with native
// rcp/exp. gelu abs err < 1e-6, budget 2.67e-5.
__device__ __forceinline__ float gelu_fast(float x) {
    float az = fabsf(x) * 0.70710678118654752f;
    float t = __builtin_amdgcn_rcpf(fmaf(0.3275911f, az, 1.0f));
    float p = fmaf(1.061405429f, t, -1.453152027f);
    p = fmaf(p, t, 1.421413741f);
    p = fmaf(p, t, -0.284496736f);
    p = fmaf(p, t, 0.254829592f);
    p = p * t;
    float e = __expf(-az * az);
    float erfa = fmaf(-p, e, 1.0f);   // erf(|x|/sqrt2)
    float erfs = copysignf(erfa, x);
    return 0.5f * x * (1.0f + erfs);
}

// round-to-nearest-even f32 -> bf16 bits
__device__ __forceinline__ unsigned short f2bf(float v) {
    unsigned u = __float_as_uint(v);
    u += 0x7fffu + ((u >> 16) & 1u);
    return (unsigned short)(u >> 16);
}
__device__ __forceinline__ float bf2f(unsigned short h) {
    return __uint_as_float(((unsigned)h) << 16);
}
__device__ __forceinline__ void split2(float v, unsigned short& hi, unsigned short& lo) {
    hi = f2bf(v);
    lo = f2bf(v - bf2f(hi));
}

// ---------------- row-normalize + split X; zero s/d buffers; init deg ----------------
__global__ __launch_bounds__(256) void norm_k(const float* __restrict__ X,
                                              unsigned short* __restrict__ Xh,
                                              unsigned short* __restrict__ Xl,
                                              float* __restrict__ sdZero,  // 6*NN floats
                                              int* __restrict__ deg) {
    int t = threadIdx.x;
    int bid = blockIdx.x;  // 0..4999
    if (t < 24) sdZero[bid * 24 + t] = 0.0f;
    if (t >= 32 && t < 36) deg[bid * 4 + (t - 32)] = 1;

    int wave = (bid * 256 + t) >> 6;
    int lane = t & 63;
    const float4 v = *(const float4*)&X[wave * DD + lane * 4];
    float ss = v.x * v.x + v.y * v.y + v.z * v.z + v.w * v.w;
    for (int off = 32; off > 0; off >>= 1) ss += __shfl_down(ss, off, 64);
    ss = __shfl(ss, 0, 64);
    float n = sqrtf(ss);
    if (n == 0.0f) n = 1e-8f;
    float inv = 1.0f / n;
    float o[4] = {v.x * inv, v.y * inv, v.z * inv, v.w * inv};
    ushort4 hv, lv;
    split2(o[0], hv.x, lv.x);
    split2(o[1], hv.y, lv.y);
    split2(o[2], hv.z, lv.z);
    split2(o[3], hv.w, lv.w);
    *(ushort4*)&Xh[wave * DD + lane * 4] = hv;
    *(ushort4*)&Xl[wave * DD + lane * 4] = lv;
}

// ---------------- W transpose + hi/lo split for all 3 layers (z = layer) ----------------
__global__ __launch_bounds__(256) void splitw_k(const float* __restrict__ W1, const float* __restrict__ W2,
                                                const float* __restrict__ W3, unsigned short* __restrict__ Whl) {
    __shared__ float tile[64][65];
    int t = threadIdx.x;
    int k0 = blockIdx.x * 64;
    int c0 = blockIdx.y * 64;
    int z = blockIdx.z;
    const float* W = (z == 0) ? W1 : (z == 1) ? W2 : W3;
    unsigned short* Wht = Whl + (size_t)z * 2 * DD * DD;
    unsigned short* Wlt = Wht + DD * DD;
#pragma unroll
    for (int i = 0; i < 16; ++i) {
        int idx = t + i * 256;
        int r = idx >> 6, c = idx & 63;
        tile[r][c] = W[(k0 + r) * DD + c0 + c];
    }
    __syncthreads();
#pragma unroll
    for (int i = 0; i < 16; ++i) {
        int idx = t + i * 256;
        int r = idx >> 6, c = idx & 63;
        float v = tile[c][r];
        unsigned short hi, lo;
        split2(v, hi, lo);
        Wht[(c0 + r) * DD + k0 + c] = hi;
        Wlt[(c0 + r) * DD + k0 + c] = lo;
    }
}

// ---------------- CSR build ----------------
__global__ void count_k(const int* __restrict__ ei, int* deg) {
    int e = blockIdx.x * 256 + threadIdx.x;
    if (e < EE) atomicAdd(&deg[ei[EE + e]], 1);
}

#define SCAN_T 1024
#define ITEMS 20
__global__ __launch_bounds__(SCAN_T) void scan_k(const int* __restrict__ deg, int* __restrict__ offs,
                                                 int* __restrict__ cursor, int* __restrict__ csr) {
    __shared__ int part[SCAN_T];
    int t = threadIdx.x;
    int base = t * ITEMS;
    int local[ITEMS];
    int sum = 0;
#pragma unroll
    for (int i = 0; i < ITEMS; ++i) {
        int idx = base + i;
        int v = (idx < NN) ? deg[idx] : 0;
        local[i] = v;
        sum += v;
    }
    part[t] = sum;
    __syncthreads();
    for (int s = 1; s < SCAN_T; s <<= 1) {
        int v = (t >= s) ? part[t - s] : 0;
        __syncthreads();
        part[t] += v;
        __syncthreads();
    }
    int run = (t == 0) ? 0 : part[t - 1];
#pragma unroll
    for (int i = 0; i < ITEMS; ++i) {
        int idx = base + i;
        if (idx < NN) {
            offs[idx] = run;
            cursor[idx] = run + 1;  // slot 0 of segment = self loop
            csr[run] = idx;
            run += local[i];
        }
    }
    if (t == SCAN_T - 1) offs[NN] = part[SCAN_T - 1];
}

__global__ void fill_k(const int* __restrict__ ei, int* cursor, int* __restrict__ csr) {
    int e = blockIdx.x * 256 + threadIdx.x;
    if (e < EE) {
        int s = ei[e];
        int d = ei[EE + e];
        int p = atomicAdd(&cursor[d], 1);
        csr[p] = s;
    }
}

// ---------------- MFMA GEMM + fused s,d epilogue ----------------
// 64x128 tile, 4 waves; A fragments direct from global; B staged in LDS w/ reg dbuf.
#define LDB 40
__global__ __launch_bounds__(256) void gemm_sd(const unsigned short* __restrict__ Xh,
                                               const unsigned short* __restrict__ Xl,
                                               const unsigned short* __restrict__ Bh,
                                               const unsigned short* __restrict__ Bl,
                                               const float* __restrict__ a_s,
                                               const float* __restrict__ a_d,
                                               float* __restrict__ H,
                                               float* __restrict__ sArr,
                                               float* __restrict__ dArr) {
    __shared__ unsigned short sBh[128 * LDB], sBl[128 * LDB];
    int t = threadIdx.x;
    int m0 = blockIdx.x * 64;
    int n0 = blockIdx.y * 128;
    int w = t >> 6, l = t & 63;
    int rofs = l & 15, kch = l >> 4;

    f32x4 acc[8] = {};

    int c1 = t, c2 = t + 256;
    int br1 = c1 >> 2, bo1 = (c1 & 3) * 8;
    int br2 = c2 >> 2, bo2 = (c2 & 3) * 8;
    const unsigned short* Bh1 = &Bh[(n0 + br1) * DD + bo1];
    const unsigned short* Bh2 = &Bh[(n0 + br2) * DD + bo2];
    const unsigned short* Bl1 = &Bl[(n0 + br1) * DD + bo1];
    const unsigned short* Bl2 = &Bl[(n0 + br2) * DD + bo2];
    bf8 rbh1 = *(const bf8*)Bh1;
    bf8 rbh2 = *(const bf8*)Bh2;
    bf8 rbl1 = *(const bf8*)Bl1;
    bf8 rbl2 = *(const bf8*)Bl2;

    int arow = m0 + w * 16 + rofs;
    bool aval = arow < NN;
    const unsigned short* Ahp = &Xh[(size_t)arow * DD + kch * 8];
    const unsigned short* Alp = &Xl[(size_t)arow * DD + kch * 8];
    bf8 zero = {0, 0, 0, 0, 0, 0, 0, 0};
    bf8 ah = aval ? *(const bf8*)Ahp : zero;
    bf8 al = aval ? *(const bf8*)Alp : zero;

    for (int k0 = 0; k0 < DD; k0 += 32) {
        if (k0) __syncthreads();
        *(bf8*)&sBh[br1 * LDB + bo1] = rbh1;
        *(bf8*)&sBh[br2 * LDB + bo2] = rbh2;
        *(bf8*)&sBl[br1 * LDB + bo1] = rbl1;
        *(bf8*)&sBl[br2 * LDB + bo2] = rbl2;
        __syncthreads();
        int kn = k0 + 32;
        bf8 nah = zero, nal = zero;
        if (kn < DD) {
            rbh1 = *(const bf8*)(Bh1 + kn);
            rbh2 = *(const bf8*)(Bh2 + kn);
            rbl1 = *(const bf8*)(Bl1 + kn);
            rbl2 = *(const bf8*)(Bl2 + kn);
            if (aval) {
                nah = *(const bf8*)(Ahp + kn);
                nal = *(const bf8*)(Alp + kn);
            }
        }
#pragma unroll
        for (int nt = 0; nt < 8; ++nt) {
            int r = nt * 16 + rofs;
            bf8 bh = *(const bf8*)&sBh[r * LDB + kch * 8];
            bf8 bl = *(const bf8*)&sBl[r * LDB + kch * 8];
            acc[nt] = __builtin_amdgcn_mfma_f32_16x16x32_bf16(ah, bh, acc[nt], 0, 0, 0);
            acc[nt] = __builtin_amdgcn_mfma_f32_16x16x32_bf16(ah, bl, acc[nt], 0, 0, 0);
            acc[nt] = __builtin_amdgcn_mfma_f32_16x16x32_bf16(al, bh, acc[nt], 0, 0, 0);
        }
        ah = nah;
        al = nal;
    }
    // C/D layout: col = lane&15, row = (lane>>4)*4 + reg  [m89]
    int row0 = m0 + w * 16 + (l >> 4) * 4;
    int colb = l & 15;
    float sp[4] = {0, 0, 0, 0}, dp[4] = {0, 0, 0, 0};
#pragma unroll
    for (int nt = 0; nt < 8; ++nt) {
        int cc = n0 + nt * 16 + colb;
        float vas = a_s[cc], vad = a_d[cc];
#pragma unroll
        for (int r = 0; r < 4; ++r) {
            int row = row0 + r;
            if (row < NN) H[(size_t)row * DD + cc] = acc[nt][r];
            sp[r] += acc[nt][r] * vas;
            dp[r] += acc[nt][r] * vad;
        }
    }
#pragma unroll
    for (int m = 1; m < 16; m <<= 1) {
#pragma unroll
        for (int r = 0; r < 4; ++r) {
            sp[r] += __shfl_xor(sp[r], m, 64);
            dp[r] += __shfl_xor(dp[r], m, 64);
        }
    }
    if (colb == 0) {
#pragma unroll
        for (int r = 0; r < 4; ++r) {
            int row = row0 + r;
            if (row < NN) {
                atomicAdd(&sArr[row], sp[r]);
                atomicAdd(&dArr[row], dp[r]);
            }
        }
    }
}

// ---------------- normalized edge weights -> packed {src, w} pairs ----------------
__global__ __launch_bounds__(256) void wnorm_k(const float* __restrict__ sArr, const float* __restrict__ dArr,
                                               const int* __restrict__ offs, const int* __restrict__ csr,
                                               int2* __restrict__ ewn) {
    int t = threadIdx.x;
    int sub = t & 7;
    int dst = blockIdx.x * 32 + (t >> 3);
    int beg = offs[dst], end = offs[dst + 1];
    float dd = dArr[dst];
    float den = 0.0f;
    for (int e = beg + sub; e < end; e += 8) {
        int s = csr[e];
        float a = sArr[s] + dd;
        a = (a > 0.0f) ? a : 0.2f * a;
        float w = __expf(a);
        ewn[e] = make_int2(s, __float_as_int(w));
        den += w;
    }
    den += __shfl_xor(den, 1, 64);
    den += __shfl_xor(den, 2, 64);
    den += __shfl_xor(den, 4, 64);
    float inv = 1.0f / den;
    float* wp = (float*)ewn;
    for (int e = beg + sub; e < end; e += 8) wp[2 * e + 1] *= inv;
}

// ---------------- strip SpMM + bias + gelu + split (thread-per-(dst,chunk)) ----------------
// grid (8, 625): blockIdx.x = 32-dim strip (XCD pin: linear%8 = strip, 2.5 MB
// slab per XCD L2). 32 dsts/block, 8 threads/dst, each thread owns a float4
// chunk and walks its dst's edge list unroll-4 (4 independent chains). Zero
// cross-lane ops; every lane runs the full epilogue (4 gelu) and does
// perfectly vectorized 8B/16B stores. Weights pre-normalized in ewn pairs.
__global__ __launch_bounds__(256) void spmm_k(const float* __restrict__ H, const int2* __restrict__ ewn,
                                              const int* __restrict__ offs, const float* __restrict__ bias,
                                              unsigned short* __restrict__ Oh,
                                              unsigned short* __restrict__ Ol,
                                              float* __restrict__ outf32) {
    int t = threadIdx.x;
    int sub = t & 7;
    int dst = blockIdx.y * 32 + (t >> 3);
    int dim = blockIdx.x * 32 + sub * 4;

    int beg = offs[dst], end = offs[dst + 1];
    const float* Hs = H + dim;

    float4 A0 = make_float4(0, 0, 0, 0), A1 = A0, A2 = A0, A3 = A0;

    int e = beg;
    for (; e + 3 < end; e += 4) {
        int2 p0 = ewn[e], p1 = ewn[e + 1], p2 = ewn[e + 2], p3 = ewn[e + 3];
        float w0 = __int_as_float(p0.y), w1 = __int_as_float(p1.y);
        float w2 = __int_as_float(p2.y), w3 = __int_as_float(p3.y);
        const float4 h0 = *(const float4*)&Hs[(size_t)p0.x * DD];
        const float4 h1 = *(const float4*)&Hs[(size_t)p1.x * DD];
        const float4 h2 = *(const float4*)&Hs[(size_t)p2.x * DD];
        const float4 h3 = *(const float4*)&Hs[(size_t)p3.x * DD];
        A0.x += w0 * h0.x; A0.y += w0 * h0.y; A0.z += w0 * h0.z; A0.w += w0 * h0.w;
        A1.x += w1 * h1.x; A1.y += w1 * h1.y; A1.z += w1 * h1.z; A1.w += w1 * h1.w;
        A2.x += w2 * h2.x; A2.y += w2 * h2.y; A2.z += w2 * h2.z; A2.w += w2 * h2.w;
        A3.x += w3 * h3.x; A3.y += w3 * h3.y; A3.z += w3 * h3.z; A3.w += w3 * h3.w;
    }
    for (; e < end; ++e) {
        int2 p0 = ewn[e];
        float w0 = __int_as_float(p0.y);
        const float4 h0 = *(const float4*)&Hs[(size_t)p0.x * DD];
        A0.x += w0 * h0.x; A0.y += w0 * h0.y; A0.z += w0 * h0.z; A0.w += w0 * h0.w;
    }

    const float4 b = *(const float4*)&bias[dim];
    float o0 = gelu_fast(A0.x + A1.x + A2.x + A3.x + b.x);
    float o1 = gelu_fast(A0.y + A1.y + A2.y + A3.y + b.y);
    float o2 = gelu_fast(A0.z + A1.z + A2.z + A3.z + b.z);
    float o3 = gelu_fast(A0.w + A1.w + A2.w + A3.w + b.w);

    ushort4 hv, lv;
    split2(o0, hv.x, lv.x);
    split2(o1, hv.y, lv.y);
    split2(o2, hv.z, lv.z);
    split2(o3, hv.w, lv.w);
    *(ushort4*)&Oh[dst * DD + dim] = hv;
    *(ushort4*)&Ol[dst * DD + dim] = lv;
    if (outf32) {
        float4 o = make_float4(o0, o1, o2, o3);
        *(float4*)&outf32[dst * DD + dim] = o;
    }
}

extern "C" void kernel_launch(void* const* d_in, const int* in_sizes, int n_in,
                              void* d_out, int out_size, void* d_ws, size_t ws_size,
                              hipStream_t stream) {
    const float* x  = (const float*)d_in[0];
    const int* ei   = (const int*)d_in[1];
    const float* W1 = (const float*)d_in[4];
    const float* as1 = (const float*)d_in[5];
    const float* ad1 = (const float*)d_in[6];
    const float* b1 = (const float*)d_in[7];
    const float* W2 = (const float*)d_in[8];
    const float* as2 = (const float*)d_in[9];
    const float* ad2 = (const float*)d_in[10];
    const float* b2 = (const float*)d_in[11];
    const float* W3 = (const float*)d_in[12];
    const float* as3 = (const float*)d_in[13];
    const float* ad3 = (const float*)d_in[14];
    const float* b3 = (const float*)d_in[15];

    float* H = (float*)d_ws;                                      // [N,256] f32
    unsigned short* Xh = (unsigned short*)(H + (size_t)NN * DD);  // [N,256] bf16
    unsigned short* Xl = Xh + (size_t)NN * DD;
    unsigned short* Whl = Xl + (size_t)NN * DD;                   // 6 x [256,256]
    float* sd = (float*)(Whl + (size_t)6 * DD * DD);              // 6*NN: s1,d1,s2,d2,s3,d3
    int* offs = (int*)(sd + (size_t)6 * NN);                      // [N+1]
    int* cursor = offs + (NN + 1);                                // [N]
    int* csr = cursor + NN;                                       // [ETOT]
    int* deg = csr + ETOT;                                        // [N]
    int2* ewn = (int2*)(deg + NN);                                // [ETOT] {src, w}

    float* sA1 = sd,           *dA1 = sd + NN;
    float* sA2 = sd + 2 * NN,  *dA2 = sd + 3 * NN;
    float* sA3 = sd + 4 * NN,  *dA3 = sd + 5 * NN;
    unsigned short* Wt1 = Whl;
    unsigned short* Wt2 = Whl + (size_t)2 * DD * DD;
    unsigned short* Wt3 = Whl + (size_t)4 * DD * DD;

    // 1: normalize+split X, zero s/d, init deg
    norm_k<<<NN / 4, 256, 0, stream>>>(x, Xh, Xl, sd, deg);
    // 2-4: CSR build
    count_k<<<(EE + 255) / 256, 256, 0, stream>>>(ei, deg);
    scan_k<<<1, SCAN_T, 0, stream>>>(deg, offs, cursor, csr);
    fill_k<<<(EE + 255) / 256, 256, 0, stream>>>(ei, cursor, csr);
    // 5: all W transposes+splits
    splitw_k<<<dim3(4, 4, 3), 256, 0, stream>>>(W1, W2, W3, Whl);

    dim3 ggrid((NN + 63) / 64, DD / 128);
    dim3 sgrid(DD / 32, NN / 32);  // x = strip (XCD pin), y = dst group

    // layer 1
    gemm_sd<<<ggrid, 256, 0, stream>>>(Xh, Xl, Wt1, Wt1 + DD * DD, as1, ad1, H, sA1, dA1);
    wnorm_k<<<NN / 32, 256, 0, stream>>>(sA1, dA1, offs, csr, ewn);
    spmm_k<<<sgrid, 256, 0, stream>>>(H, ewn, offs, b1, Xh, Xl, nullptr);
    // layer 2
    gemm_sd<<<ggrid, 256, 0, stream>>>(Xh, Xl, Wt2, Wt2 + DD * DD, as2, ad2, H, sA2, dA2);
    wnorm_k<<<NN / 32, 256, 0, stream>>>(sA2, dA2, offs, csr, ewn);
    spmm_k<<<sgrid, 256, 0, stream>>>(H, ewn, offs, b2, Xh, Xl, nullptr);
    // layer 3
    gemm_sd<<<ggrid, 256, 0, stream>>>(Xh, Xl, Wt3, Wt3 + DD * DD, as3, ad3, H, sA3, dA3);
    wnorm_k<<<NN / 32, 256, 0, stream>>>(sA3, dA3, offs, csr, ewn);
    spmm_k<<<sgrid, 256, 0, stream>>>(H, ewn, offs, b3, Xh, Xl, (float*)d_out);
}